// Round 2
// baseline (807.636 us; speedup 1.0000x reference)
//
#include <hip/hip_runtime.h>
#include <stdint.h>

// Problem constants
#define Bsz 1024
#define Tn  20
#define Hn  768
#define G4n 3072   // 4*H

// Workspace layout (floats):
//  [0..31]     Sh[t]    : sum of h after step t (atomic accum)
//  [32..63]    Sev[t]   : sum of batch_event[:,t,:]
//  [64..95]    cnt[t]   : barrier arrival counters (uint)
//  [128..]     rowsum[20][3072]
//  [+61440]    biassum[20][3072]
//  [+61440]    c0 handoff [1024][768]
#define WS_SH   0
#define WS_SEV  32
#define WS_CNT  64
#define WS_RS   128
#define WS_BS   (128 + Tn*G4n)
#define WS_C    (128 + 2*Tn*G4n)

// merged-kernel block ranges
#define NB_GEMM   768
#define NB_ROWSUM 14592
#define NB_BIAS   240
#define NB_SEV    1216
#define NB_TOTAL  (NB_GEMM + NB_ROWSUM + NB_BIAS + NB_SEV)

typedef float  floatx4 __attribute__((ext_vector_type(4)));
typedef short  bfrag8  __attribute__((ext_vector_type(8)));

__device__ __forceinline__ float wave_reduce(float v){
#pragma unroll
    for (int o = 32; o > 0; o >>= 1) v += __shfl_down(v, o, 64);
    return v;
}
__device__ __forceinline__ float sigf(float x){ return 1.0f/(1.0f+__expf(-x)); }
__device__ __forceinline__ float tanhfast(float x){ return 2.0f/(1.0f+__expf(-2.0f*x)) - 1.0f; }
__device__ __forceinline__ unsigned short f2bf(float f){
    uint32_t u = __float_as_uint(f);
    return (unsigned short)((u + 0x7fffu + ((u>>16)&1u)) >> 16);
}
__device__ __forceinline__ float bf2f(unsigned short h){ return __uint_as_float(((uint32_t)h)<<16); }

// ---------------- K0: zero scalar slots + barrier counters ----------------
__global__ void k_init(float* __restrict__ ws){
    if (threadIdx.x < 128) ws[threadIdx.x] = 0.0f;   // Sh, Sev, cnt (bit-zero)
}

// ---------------- K1 (merged): t=0 GEMM + rowsums + biassums + Sev ----------------
// blocks [0,768): bf16x3 MFMA GEMM for t=0 gates -> c0, Sh[0]
// blocks [768, 768+14592): rowsum over W_hh rows, t=1..19 (wave per row)
// then 240 biassum blocks, then 1216 Sev blocks.
__global__ __launch_bounds__(256) void k_pre(
    const float* __restrict__ price, const float* __restrict__ ev,
    const float* __restrict__ wih,   const float* __restrict__ whh,
    const float* __restrict__ bih,   const float* __restrict__ bhh,
    float* __restrict__ ws)
{
    __shared__ __align__(16) char smraw[4*64*56*2 + 16];
    unsigned short* Ah = (unsigned short*)smraw;
    unsigned short* Al = Ah + 64*56;
    unsigned short* Bh = Al + 64*56;
    unsigned short* Bl = Bh + 64*56;
    float* redk = (float*)(smraw + 4*64*56*2);
    float* red  = (float*)smraw;

    int blk = blockIdx.x, tid = threadIdx.x;

    if (blk < NB_GEMM) {
        // ----- GEMM for t=0 -----
        float* Sh   = ws + WS_SH;
        float* cbuf = ws + WS_C;
        int bt = blk / 48, kt = blk % 48;
        int b0 = bt*64, k0 = kt*16;
        int w = tid >> 6, lane = tid & 63;
        int q = lane >> 4, col = lane & 15;

        int srow = tid >> 2;
        int kkoff = (tid & 3) * 8;
        int g_s = srow >> 4, rr = srow & 15;
        const float* aRow = ev  + (size_t)(b0 + srow)*(Tn*Hn);
        const float* bRow = whh + (size_t)(g_s*Hn + k0 + rr)*Hn;

        floatx4 acc[4];
#pragma unroll
        for (int g = 0; g < 4; ++g) acc[g] = (floatx4){0.f,0.f,0.f,0.f};

        for (int kk0 = 0; kk0 < Hn; kk0 += 32) {
            {
                const float* p = aRow + kk0 + kkoff;
                float4 v0 = *(const float4*)p;
                float4 v1 = *(const float4*)(p+4);
                float f[8] = {v0.x,v0.y,v0.z,v0.w,v1.x,v1.y,v1.z,v1.w};
                bfrag8 hv, lv;
#pragma unroll
                for (int i = 0; i < 8; ++i) {
                    unsigned short hb = f2bf(f[i]);
                    hv[i] = (short)hb;
                    lv[i] = (short)f2bf(f[i] - bf2f(hb));
                }
                *(bfrag8*)&Ah[srow*56 + kkoff] = hv;
                *(bfrag8*)&Al[srow*56 + kkoff] = lv;
                const float* pb = bRow + kk0 + kkoff;
                float4 u0 = *(const float4*)pb;
                float4 u1 = *(const float4*)(pb+4);
                float fb[8] = {u0.x,u0.y,u0.z,u0.w,u1.x,u1.y,u1.z,u1.w};
#pragma unroll
                for (int i = 0; i < 8; ++i) {
                    unsigned short hb = f2bf(fb[i]);
                    hv[i] = (short)hb;
                    lv[i] = (short)f2bf(fb[i] - bf2f(hb));
                }
                *(bfrag8*)&Bh[srow*56 + kkoff] = hv;
                *(bfrag8*)&Bl[srow*56 + kkoff] = lv;
            }
            __syncthreads();

            bfrag8 ah = *(const bfrag8*)&Ah[(w*16 + col)*56 + q*8];
            bfrag8 al = *(const bfrag8*)&Al[(w*16 + col)*56 + q*8];
#pragma unroll
            for (int g = 0; g < 4; ++g) {
                bfrag8 bh = *(const bfrag8*)&Bh[(g*16 + col)*56 + q*8];
                bfrag8 bl = *(const bfrag8*)&Bl[(g*16 + col)*56 + q*8];
                acc[g] = __builtin_amdgcn_mfma_f32_16x16x32_bf16(ah, bh, acc[g], 0,0,0);
                acc[g] = __builtin_amdgcn_mfma_f32_16x16x32_bf16(ah, bl, acc[g], 0,0,0);
                acc[g] = __builtin_amdgcn_mfma_f32_16x16x32_bf16(al, bh, acc[g], 0,0,0);
            }
            __syncthreads();
        }

        float hsum = 0.f;
#pragma unroll
        for (int r = 0; r < 4; ++r) {
            int b = b0 + w*16 + q*4 + r;
            float4 xv = *(const float4*)(price + (size_t)b*(Tn*4));
            float gates[4];
#pragma unroll
            for (int g = 0; g < 4; ++g) {
                int j = g*Hn + k0 + col;
                float4 wv = *(const float4*)(wih + (size_t)j*4);
                gates[g] = acc[g][r] + xv.x*wv.x + xv.y*wv.y + xv.z*wv.z + xv.w*wv.w
                         + bih[j] + bhh[j];
            }
            float c0 = sigf(gates[0]) * tanhfast(gates[2]);
            float h0 = sigf(gates[3]) * tanhfast(c0);
            cbuf[(size_t)b*Hn + k0 + col] = c0;
            hsum += h0;
        }
        hsum = wave_reduce(hsum);
        if (lane == 0) redk[w] = hsum;
        __syncthreads();
        if (tid == 0) atomicAdd(&Sh[0], redk[0]+redk[1]+redk[2]+redk[3]);
        return;
    }

    blk -= NB_GEMM;
    float* Sev     = ws + WS_SEV;
    float* rowsum  = ws + WS_RS;
    float* biassum = ws + WS_BS;

    if (blk < NB_ROWSUM) {                   // rowsum: rows for t=1..19
        int r    = blk*4 + (tid>>6);
        int lane = tid & 63;
        int t    = 1 + r/G4n;
        int j    = r - (t-1)*G4n;
        const float* base = whh + (size_t)t*G4n*Hn + (size_t)j*Hn;
        float s = 0.f;
#pragma unroll
        for (int i = 0; i < 3; ++i) {
            float4 v = *(const float4*)(base + (size_t)(lane + 64*i)*4);
            s += v.x + v.y + v.z + v.w;
        }
        s = wave_reduce(s);
        if (lane == 0) rowsum[t*G4n + j] = s;
    } else if (blk < NB_ROWSUM + NB_BIAS) {  // biassum
        int idx = (blk - NB_ROWSUM)*256 + tid;
        if (idx < Tn*G4n) biassum[idx] = bih[idx] + bhh[idx];
    } else {                                 // Sev[t], t=1..19, 64 blocks per t
        int sb = blk - NB_ROWSUM - NB_BIAS;
        int t  = 1 + (sb >> 6);
        int b0 = (sb & 63) * 16;
        float s = 0.f;
        for (int bb = 0; bb < 16; ++bb) {
            const float* base = ev + (size_t)(b0+bb)*(Tn*Hn) + (size_t)t*Hn;
            s += base[tid] + base[tid+256] + base[tid+512];
        }
        s = wave_reduce(s);
        if ((tid & 63) == 0) red[tid>>6] = s;
        __syncthreads();
        if (tid == 0) atomicAdd(&Sev[t], red[0]+red[1]+red[2]+red[3]);
    }
}

// ---------------- K2: persistent fused recurrence, t=1..19 ----------------
// 256 blocks x 768 threads; block owns b = blockIdx + 256e (e=0..3), k = tid.
// c stays in registers. Per-step global barrier: atomicAdd Sh[t] + cnt spin.
__global__ __launch_bounds__(768) void k_steps(
    const float* __restrict__ price, const float* __restrict__ wih,
    const float* __restrict__ fcw,   const float* __restrict__ fcb,
    float* __restrict__ ws, float* __restrict__ out)
{
    __shared__ float pr[4][80];      // price rows for this block's 4 b's
    __shared__ float red[12];
    __shared__ float redF[4][12];
    __shared__ float shx;

    float* Sh  = ws + WS_SH;
    float* Sev = ws + WS_SEV;
    unsigned int* cnt = (unsigned int*)(ws + WS_CNT);
    const float* rowsum  = ws + WS_RS;
    const float* biassum = ws + WS_BS;
    float* cbuf = ws + WS_C;

    int blk = blockIdx.x, tid = threadIdx.x;
    int lane = tid & 63, wid = tid >> 6;
    int k = tid;

    if (tid < 320) {
        int e = tid / 80, r = tid - e*80;
        pr[e][r] = price[(size_t)(blk + 256*e)*(Tn*4) + r];
    }

    float c[4];
#pragma unroll
    for (int e = 0; e < 4; ++e)
        c[e] = cbuf[(size_t)(blk + 256*e)*Hn + k];

    float fcwk = fcw[k];
    float fcb0 = fcb[0];

    float hsum_prev = 0.f;
    float vout[4] = {0.f,0.f,0.f,0.f};

    for (int t = 1; t < Tn; ++t) {
        // preload step-t coefficients (independent of hx -> overlaps barrier)
        const float* wih_t = wih + (size_t)t*G4n*4;
        float4 wv[4]; float rsv[4], bsv[4];
#pragma unroll
        for (int g = 0; g < 4; ++g) {
            int j = g*Hn + k;
            wv[g]  = *(const float4*)(wih_t + (size_t)j*4);
            rsv[g] = rowsum[t*G4n + j];
            bsv[g] = biassum[t*G4n + j];
        }

        // obtain hx_t = Sev[t] + Sh[t-1]
        if (t >= 2) {
            float v = wave_reduce(hsum_prev);
            if (lane == 0) red[wid] = v;
        }
        __syncthreads();
        if (tid == 0) {
            if (t >= 2) {
                float tot = 0.f;
#pragma unroll
                for (int i = 0; i < 12; ++i) tot += red[i];
                atomicAdd(&Sh[t-1], tot);
                __threadfence();
                __hip_atomic_fetch_add(&cnt[t-1], 1u, __ATOMIC_RELEASE, __HIP_MEMORY_SCOPE_AGENT);
                while (__hip_atomic_load(&cnt[t-1], __ATOMIC_ACQUIRE, __HIP_MEMORY_SCOPE_AGENT) < 256u)
                    __builtin_amdgcn_s_sleep(2);
            }
            shx = Sev[t] + __hip_atomic_load(&Sh[t-1], __ATOMIC_RELAXED, __HIP_MEMORY_SCOPE_AGENT);
        }
        __syncthreads();
        float hx = shx;

        float cb[4];
#pragma unroll
        for (int g = 0; g < 4; ++g) cb[g] = bsv[g] + hx*rsv[g];

        float hsum = 0.f;
#pragma unroll
        for (int e = 0; e < 4; ++e) {
            float x0 = pr[e][t*4+0], x1 = pr[e][t*4+1], x2 = pr[e][t*4+2], x3 = pr[e][t*4+3];
            float gi = x0*wv[0].x + x1*wv[0].y + x2*wv[0].z + x3*wv[0].w + cb[0];
            float gf = x0*wv[1].x + x1*wv[1].y + x2*wv[1].z + x3*wv[1].w + cb[1];
            float gg = x0*wv[2].x + x1*wv[2].y + x2*wv[2].z + x3*wv[2].w + cb[2];
            float go = x0*wv[3].x + x1*wv[3].y + x2*wv[3].z + x3*wv[3].w + cb[3];
            float cn = sigf(gf)*c[e] + sigf(gi)*tanhfast(gg);
            c[e] = cn;
            float h = sigf(go)*tanhfast(cn);
            hsum += h;
            if (t == Tn-1) vout[e] = wave_reduce(h * fcwk);
        }
        hsum_prev = hsum;
    }

    // epilogue: out[b] = h19[b,:].fc_w + fc_b
    if (lane == 0) {
#pragma unroll
        for (int e = 0; e < 4; ++e) redF[e][wid] = vout[e];
    }
    __syncthreads();
    if (tid < 4) {
        float tot = 0.f;
#pragma unroll
        for (int i = 0; i < 12; ++i) tot += redF[tid][i];
        out[blk + 256*tid] = tot + fcb0;
    }
}

extern "C" void kernel_launch(void* const* d_in, const int* in_sizes, int n_in,
                              void* d_out, int out_size, void* d_ws, size_t ws_size,
                              hipStream_t stream)
{
    const float* price = (const float*)d_in[0];
    const float* ev    = (const float*)d_in[1];
    const float* wih   = (const float*)d_in[2];
    const float* whh   = (const float*)d_in[3];
    const float* bih   = (const float*)d_in[4];
    const float* bhh   = (const float*)d_in[5];
    const float* fcw   = (const float*)d_in[6];
    const float* fcb   = (const float*)d_in[7];
    float* out = (float*)d_out;
    float* ws  = (float*)d_ws;

    k_init<<<1, 128, 0, stream>>>(ws);
    k_pre <<<NB_TOTAL, 256, 0, stream>>>(price, ev, wih, whh, bih, bhh, ws);
    k_steps<<<256, 768, 0, stream>>>(price, wih, fcw, fcb, ws, out);
}

// Round 3
// 711.103 us; speedup vs baseline: 1.1358x; 1.1358x over previous
//
#include <hip/hip_runtime.h>
#include <stdint.h>

// Problem constants
#define Bsz 1024
#define Tn  20
#define Hn  768
#define G4n 3072   // 4*H

// Workspace layout (floats):
//  [0..31]     Sh[t]    : sum of h after step t (atomic accum)
//  [32..63]    Sev[t]   : sum of batch_event[:,t,:]
//  [64..95]    cnt[t]   : barrier arrival counters (uint)
//  [128..]     rowsum[20][3072]
//  [+61440]    biassum[20][3072]
//  [+61440]    c0 handoff [1024][768]
#define WS_SH   0
#define WS_SEV  32
#define WS_CNT  64
#define WS_RS   128
#define WS_BS   (128 + Tn*G4n)
#define WS_C    (128 + 2*Tn*G4n)

// merged-kernel block ranges
#define NB_GEMM   768
#define NB_ROWSUM 14592
#define NB_BIAS   240
#define NB_SEV    1216
#define NB_TOTAL  (NB_GEMM + NB_ROWSUM + NB_BIAS + NB_SEV)

typedef float  floatx4 __attribute__((ext_vector_type(4)));
typedef short  bfrag8  __attribute__((ext_vector_type(8)));

__device__ __forceinline__ float wave_reduce(float v){
#pragma unroll
    for (int o = 32; o > 0; o >>= 1) v += __shfl_down(v, o, 64);
    return v;
}
__device__ __forceinline__ float sigf(float x){ return 1.0f/(1.0f+__expf(-x)); }
__device__ __forceinline__ float tanhfast(float x){ return 2.0f/(1.0f+__expf(-2.0f*x)) - 1.0f; }
__device__ __forceinline__ unsigned short f2bf(float f){
    uint32_t u = __float_as_uint(f);
    return (unsigned short)((u + 0x7fffu + ((u>>16)&1u)) >> 16);
}
__device__ __forceinline__ float bf2f(unsigned short h){ return __uint_as_float(((uint32_t)h)<<16); }

// ---------------- K0: zero scalar slots + barrier counters ----------------
__global__ void k_init(float* __restrict__ ws){
    if (threadIdx.x < 128) ws[threadIdx.x] = 0.0f;   // Sh, Sev, cnt (bit-zero)
}

// ---------------- K1 (merged): t=0 GEMM + rowsums + biassums + Sev ----------------
__global__ __launch_bounds__(256) void k_pre(
    const float* __restrict__ price, const float* __restrict__ ev,
    const float* __restrict__ wih,   const float* __restrict__ whh,
    const float* __restrict__ bih,   const float* __restrict__ bhh,
    float* __restrict__ ws)
{
    __shared__ __align__(16) char smraw[4*64*56*2 + 16];
    unsigned short* Ah = (unsigned short*)smraw;
    unsigned short* Al = Ah + 64*56;
    unsigned short* Bh = Al + 64*56;
    unsigned short* Bl = Bh + 64*56;
    float* redk = (float*)(smraw + 4*64*56*2);
    float* red  = (float*)smraw;

    int blk = blockIdx.x, tid = threadIdx.x;

    if (blk < NB_GEMM) {
        // ----- GEMM for t=0 (bf16x3 split precision) -----
        float* Sh   = ws + WS_SH;
        float* cbuf = ws + WS_C;
        int bt = blk / 48, kt = blk % 48;
        int b0 = bt*64, k0 = kt*16;
        int w = tid >> 6, lane = tid & 63;
        int q = lane >> 4, col = lane & 15;

        int srow = tid >> 2;
        int kkoff = (tid & 3) * 8;
        int g_s = srow >> 4, rr = srow & 15;
        const float* aRow = ev  + (size_t)(b0 + srow)*(Tn*Hn);
        const float* bRow = whh + (size_t)(g_s*Hn + k0 + rr)*Hn;

        floatx4 acc[4];
#pragma unroll
        for (int g = 0; g < 4; ++g) acc[g] = (floatx4){0.f,0.f,0.f,0.f};

        for (int kk0 = 0; kk0 < Hn; kk0 += 32) {
            {
                const float* p = aRow + kk0 + kkoff;
                float4 v0 = *(const float4*)p;
                float4 v1 = *(const float4*)(p+4);
                float f[8] = {v0.x,v0.y,v0.z,v0.w,v1.x,v1.y,v1.z,v1.w};
                bfrag8 hv, lv;
#pragma unroll
                for (int i = 0; i < 8; ++i) {
                    unsigned short hb = f2bf(f[i]);
                    hv[i] = (short)hb;
                    lv[i] = (short)f2bf(f[i] - bf2f(hb));
                }
                *(bfrag8*)&Ah[srow*56 + kkoff] = hv;
                *(bfrag8*)&Al[srow*56 + kkoff] = lv;
                const float* pb = bRow + kk0 + kkoff;
                float4 u0 = *(const float4*)pb;
                float4 u1 = *(const float4*)(pb+4);
                float fb[8] = {u0.x,u0.y,u0.z,u0.w,u1.x,u1.y,u1.z,u1.w};
#pragma unroll
                for (int i = 0; i < 8; ++i) {
                    unsigned short hb = f2bf(fb[i]);
                    hv[i] = (short)hb;
                    lv[i] = (short)f2bf(fb[i] - bf2f(hb));
                }
                *(bfrag8*)&Bh[srow*56 + kkoff] = hv;
                *(bfrag8*)&Bl[srow*56 + kkoff] = lv;
            }
            __syncthreads();

            bfrag8 ah = *(const bfrag8*)&Ah[(w*16 + col)*56 + q*8];
            bfrag8 al = *(const bfrag8*)&Al[(w*16 + col)*56 + q*8];
#pragma unroll
            for (int g = 0; g < 4; ++g) {
                bfrag8 bh = *(const bfrag8*)&Bh[(g*16 + col)*56 + q*8];
                bfrag8 bl = *(const bfrag8*)&Bl[(g*16 + col)*56 + q*8];
                acc[g] = __builtin_amdgcn_mfma_f32_16x16x32_bf16(ah, bh, acc[g], 0,0,0);
                acc[g] = __builtin_amdgcn_mfma_f32_16x16x32_bf16(ah, bl, acc[g], 0,0,0);
                acc[g] = __builtin_amdgcn_mfma_f32_16x16x32_bf16(al, bh, acc[g], 0,0,0);
            }
            __syncthreads();
        }

        float hsum = 0.f;
#pragma unroll
        for (int r = 0; r < 4; ++r) {
            int b = b0 + w*16 + q*4 + r;
            float4 xv = *(const float4*)(price + (size_t)b*(Tn*4));
            float gates[4];
#pragma unroll
            for (int g = 0; g < 4; ++g) {
                int j = g*Hn + k0 + col;
                float4 wv = *(const float4*)(wih + (size_t)j*4);
                gates[g] = acc[g][r] + xv.x*wv.x + xv.y*wv.y + xv.z*wv.z + xv.w*wv.w
                         + bih[j] + bhh[j];
            }
            float c0 = sigf(gates[0]) * tanhfast(gates[2]);
            float h0 = sigf(gates[3]) * tanhfast(c0);
            cbuf[(size_t)b*Hn + k0 + col] = c0;
            hsum += h0;
        }
        hsum = wave_reduce(hsum);
        if (lane == 0) redk[w] = hsum;
        __syncthreads();
        if (tid == 0) atomicAdd(&Sh[0], redk[0]+redk[1]+redk[2]+redk[3]);
        return;
    }

    blk -= NB_GEMM;
    float* Sev     = ws + WS_SEV;
    float* rowsum  = ws + WS_RS;
    float* biassum = ws + WS_BS;

    if (blk < NB_ROWSUM) {                   // rowsum: rows for t=1..19
        int r    = blk*4 + (tid>>6);
        int lane = tid & 63;
        int t    = 1 + r/G4n;
        int j    = r - (t-1)*G4n;
        const float* base = whh + (size_t)t*G4n*Hn + (size_t)j*Hn;
        float s = 0.f;
#pragma unroll
        for (int i = 0; i < 3; ++i) {
            float4 v = *(const float4*)(base + (size_t)(lane + 64*i)*4);
            s += v.x + v.y + v.z + v.w;
        }
        s = wave_reduce(s);
        if (lane == 0) rowsum[t*G4n + j] = s;
    } else if (blk < NB_ROWSUM + NB_BIAS) {  // biassum
        int idx = (blk - NB_ROWSUM)*256 + tid;
        if (idx < Tn*G4n) biassum[idx] = bih[idx] + bhh[idx];
    } else {                                 // Sev[t], t=1..19, 64 blocks per t
        int sb = blk - NB_ROWSUM - NB_BIAS;
        int t  = 1 + (sb >> 6);
        int b0 = (sb & 63) * 16;
        float s = 0.f;
        for (int bb = 0; bb < 16; ++bb) {
            const float* base = ev + (size_t)(b0+bb)*(Tn*Hn) + (size_t)t*Hn;
            s += base[tid] + base[tid+256] + base[tid+512];
        }
        s = wave_reduce(s);
        if ((tid & 63) == 0) red[tid>>6] = s;
        __syncthreads();
        if (tid == 0) atomicAdd(&Sev[t], red[0]+red[1]+red[2]+red[3]);
    }
}

// ---------------- K2: persistent fused recurrence, t=1..19 ----------------
// 256 blocks x 768 threads; block owns b = blockIdx + 256e (e=0..3), k = tid.
// c stays in registers. Per-step grid barrier: RELAXED spin + single acquire.
// (R2 lesson: ACQUIRE-in-spin invalidates the XCD's L2 every iteration ->
//  7.5 GB HBM fetch, 26 us/barrier. Spin must be relaxed.)
__global__ __launch_bounds__(768) void k_steps(
    const float* __restrict__ price, const float* __restrict__ wih,
    const float* __restrict__ fcw,   const float* __restrict__ fcb,
    float* __restrict__ ws, float* __restrict__ out)
{
    __shared__ float pr[4][80];      // price rows for this block's 4 b's
    __shared__ float red[12];
    __shared__ float redF[4][12];
    __shared__ float shx;

    float* Sh  = ws + WS_SH;
    float* Sev = ws + WS_SEV;
    unsigned int* cnt = (unsigned int*)(ws + WS_CNT);
    const float* rowsum  = ws + WS_RS;
    const float* biassum = ws + WS_BS;
    float* cbuf = ws + WS_C;

    int blk = blockIdx.x, tid = threadIdx.x;
    int lane = tid & 63, wid = tid >> 6;
    int k = tid;

    if (tid < 320) {
        int e = tid / 80, r = tid - e*80;
        pr[e][r] = price[(size_t)(blk + 256*e)*(Tn*4) + r];
    }

    float c[4];
#pragma unroll
    for (int e = 0; e < 4; ++e)
        c[e] = cbuf[(size_t)(blk + 256*e)*Hn + k];

    float fcwk = fcw[k];
    float fcb0 = fcb[0];

    float hsum_prev = 0.f;
    float vout[4] = {0.f,0.f,0.f,0.f};

    for (int t = 1; t < Tn; ++t) {
        // preload step-t coefficients (independent of hx -> overlaps barrier)
        const float* wih_t = wih + (size_t)t*G4n*4;
        float4 wv[4]; float rsv[4], bsv[4];
#pragma unroll
        for (int g = 0; g < 4; ++g) {
            int j = g*Hn + k;
            wv[g]  = *(const float4*)(wih_t + (size_t)j*4);
            rsv[g] = rowsum[t*G4n + j];
            bsv[g] = biassum[t*G4n + j];
        }

        // obtain hx_t = Sev[t] + Sh[t-1]
        if (t >= 2) {
            float v = wave_reduce(hsum_prev);
            if (lane == 0) red[wid] = v;
        }
        __syncthreads();
        if (tid == 0) {
            if (t >= 2) {
                float tot = 0.f;
#pragma unroll
                for (int i = 0; i < 12; ++i) tot += red[i];
                atomicAdd(&Sh[t-1], tot);   // device-scope, at coherence point
                // arrival: release orders the Sh add before the count
                __hip_atomic_fetch_add(&cnt[t-1], 1u, __ATOMIC_RELEASE, __HIP_MEMORY_SCOPE_AGENT);
                // RELAXED spin: no cache-maintenance per iteration
                while (__hip_atomic_load(&cnt[t-1], __ATOMIC_RELAXED, __HIP_MEMORY_SCOPE_AGENT) < 256u)
                    __builtin_amdgcn_s_sleep(2);
                // single acquire to synchronize-with all releases
                (void)__hip_atomic_load(&cnt[t-1], __ATOMIC_ACQUIRE, __HIP_MEMORY_SCOPE_AGENT);
            }
            shx = Sev[t] + __hip_atomic_load(&Sh[t-1], __ATOMIC_RELAXED, __HIP_MEMORY_SCOPE_AGENT);
        }
        __syncthreads();
        float hx = shx;

        float cb[4];
#pragma unroll
        for (int g = 0; g < 4; ++g) cb[g] = bsv[g] + hx*rsv[g];

        float hsum = 0.f;
#pragma unroll
        for (int e = 0; e < 4; ++e) {
            float x0 = pr[e][t*4+0], x1 = pr[e][t*4+1], x2 = pr[e][t*4+2], x3 = pr[e][t*4+3];
            float gi = x0*wv[0].x + x1*wv[0].y + x2*wv[0].z + x3*wv[0].w + cb[0];
            float gf = x0*wv[1].x + x1*wv[1].y + x2*wv[1].z + x3*wv[1].w + cb[1];
            float gg = x0*wv[2].x + x1*wv[2].y + x2*wv[2].z + x3*wv[2].w + cb[2];
            float go = x0*wv[3].x + x1*wv[3].y + x2*wv[3].z + x3*wv[3].w + cb[3];
            float cn = sigf(gf)*c[e] + sigf(gi)*tanhfast(gg);
            c[e] = cn;
            float h = sigf(go)*tanhfast(cn);
            hsum += h;
            if (t == Tn-1) vout[e] = wave_reduce(h * fcwk);
        }
        hsum_prev = hsum;
    }

    // epilogue: out[b] = h19[b,:].fc_w + fc_b
    if (lane == 0) {
#pragma unroll
        for (int e = 0; e < 4; ++e) redF[e][wid] = vout[e];
    }
    __syncthreads();
    if (tid < 4) {
        float tot = 0.f;
#pragma unroll
        for (int i = 0; i < 12; ++i) tot += redF[tid][i];
        out[blk + 256*tid] = tot + fcb0;
    }
}

extern "C" void kernel_launch(void* const* d_in, const int* in_sizes, int n_in,
                              void* d_out, int out_size, void* d_ws, size_t ws_size,
                              hipStream_t stream)
{
    const float* price = (const float*)d_in[0];
    const float* ev    = (const float*)d_in[1];
    const float* wih   = (const float*)d_in[2];
    const float* whh   = (const float*)d_in[3];
    const float* bih   = (const float*)d_in[4];
    const float* bhh   = (const float*)d_in[5];
    const float* fcw   = (const float*)d_in[6];
    const float* fcb   = (const float*)d_in[7];
    float* out = (float*)d_out;
    float* ws  = (float*)d_ws;

    k_init<<<1, 128, 0, stream>>>(ws);
    k_pre <<<NB_TOTAL, 256, 0, stream>>>(price, ev, wih, whh, bih, bhh, ws);
    k_steps<<<256, 768, 0, stream>>>(price, wih, fcw, fcb, ws, out);
}

// Round 4
// 419.277 us; speedup vs baseline: 1.9263x; 1.6960x over previous
//
#include <hip/hip_runtime.h>
#include <stdint.h>

// Problem constants
#define Bsz 1024
#define Tn  20
#define Hn  768
#define G4n 3072   // 4*H

// Workspace layout (floats):
//  [0..31]      Sh[t]    : sum of h (only Sh[0] used now, from k_pre atomics)
//  [32..63]     Sev[t]   : sum of batch_event[:,t,:]
//  [64..575]    part[256]: uint64 slots {token<<32 | float bits} (no RMW barrier)
//  [576..639]   bcast    : uint64 {token<<32 | hx bits}
//  [640..]      rowsum[20][3072]
//  [+61440]     biassum[20][3072]
//  [+61440]     c0 handoff [1024][768]
#define WS_SH    0
#define WS_SEV   32
#define WS_PART  64
#define WS_BCAST 576
#define WS_RS    640
#define WS_BS    (640 + Tn*G4n)
#define WS_C     (640 + 2*Tn*G4n)

// merged-kernel block ranges
#define NB_GEMM   768
#define NB_ROWSUM 14592
#define NB_BIAS   240
#define NB_SEV    1216
#define NB_TOTAL  (NB_GEMM + NB_ROWSUM + NB_BIAS + NB_SEV)

typedef float  floatx4 __attribute__((ext_vector_type(4)));
typedef short  bfrag8  __attribute__((ext_vector_type(8)));

__device__ __forceinline__ float wave_reduce(float v){
#pragma unroll
    for (int o = 32; o > 0; o >>= 1) v += __shfl_down(v, o, 64);
    return v;
}
__device__ __forceinline__ float sigf(float x){ return 1.0f/(1.0f+__expf(-x)); }
__device__ __forceinline__ float tanhfast(float x){ return 2.0f/(1.0f+__expf(-2.0f*x)) - 1.0f; }
__device__ __forceinline__ unsigned short f2bf(float f){
    uint32_t u = __float_as_uint(f);
    return (unsigned short)((u + 0x7fffu + ((u>>16)&1u)) >> 16);
}
__device__ __forceinline__ float bf2f(unsigned short h){ return __uint_as_float(((uint32_t)h)<<16); }
__device__ __forceinline__ uint64_t pack_tv(unsigned t, float v){
    return ((uint64_t)t << 32) | (uint64_t)__float_as_uint(v);
}

// ---------------- K0: zero scalar slots + token slots ----------------
__global__ void k_init(float* __restrict__ ws){
    if (threadIdx.x < 640) ws[threadIdx.x] = 0.0f;   // Sh, Sev, part, bcast
}

// ---------------- K1 (merged): t=0 GEMM + rowsums + biassums + Sev ----------------
__global__ __launch_bounds__(256) void k_pre(
    const float* __restrict__ price, const float* __restrict__ ev,
    const float* __restrict__ wih,   const float* __restrict__ whh,
    const float* __restrict__ bih,   const float* __restrict__ bhh,
    float* __restrict__ ws)
{
    __shared__ __align__(16) char smraw[4*64*56*2 + 16];
    unsigned short* Ah = (unsigned short*)smraw;
    unsigned short* Al = Ah + 64*56;
    unsigned short* Bh = Al + 64*56;
    unsigned short* Bl = Bh + 64*56;
    float* redk = (float*)(smraw + 4*64*56*2);
    float* red  = (float*)smraw;

    int blk = blockIdx.x, tid = threadIdx.x;

    if (blk < NB_GEMM) {
        // ----- GEMM for t=0 (bf16x3 split precision) -----
        float* Sh   = ws + WS_SH;
        float* cbuf = ws + WS_C;
        int bt = blk / 48, kt = blk % 48;
        int b0 = bt*64, k0 = kt*16;
        int w = tid >> 6, lane = tid & 63;
        int q = lane >> 4, col = lane & 15;

        int srow = tid >> 2;
        int kkoff = (tid & 3) * 8;
        int g_s = srow >> 4, rr = srow & 15;
        const float* aRow = ev  + (size_t)(b0 + srow)*(Tn*Hn);
        const float* bRow = whh + (size_t)(g_s*Hn + k0 + rr)*Hn;

        floatx4 acc[4];
#pragma unroll
        for (int g = 0; g < 4; ++g) acc[g] = (floatx4){0.f,0.f,0.f,0.f};

        for (int kk0 = 0; kk0 < Hn; kk0 += 32) {
            {
                const float* p = aRow + kk0 + kkoff;
                float4 v0 = *(const float4*)p;
                float4 v1 = *(const float4*)(p+4);
                float f[8] = {v0.x,v0.y,v0.z,v0.w,v1.x,v1.y,v1.z,v1.w};
                bfrag8 hv, lv;
#pragma unroll
                for (int i = 0; i < 8; ++i) {
                    unsigned short hb = f2bf(f[i]);
                    hv[i] = (short)hb;
                    lv[i] = (short)f2bf(f[i] - bf2f(hb));
                }
                *(bfrag8*)&Ah[srow*56 + kkoff] = hv;
                *(bfrag8*)&Al[srow*56 + kkoff] = lv;
                const float* pb = bRow + kk0 + kkoff;
                float4 u0 = *(const float4*)pb;
                float4 u1 = *(const float4*)(pb+4);
                float fb[8] = {u0.x,u0.y,u0.z,u0.w,u1.x,u1.y,u1.z,u1.w};
#pragma unroll
                for (int i = 0; i < 8; ++i) {
                    unsigned short hb = f2bf(fb[i]);
                    hv[i] = (short)hb;
                    lv[i] = (short)f2bf(fb[i] - bf2f(hb));
                }
                *(bfrag8*)&Bh[srow*56 + kkoff] = hv;
                *(bfrag8*)&Bl[srow*56 + kkoff] = lv;
            }
            __syncthreads();

            bfrag8 ah = *(const bfrag8*)&Ah[(w*16 + col)*56 + q*8];
            bfrag8 al = *(const bfrag8*)&Al[(w*16 + col)*56 + q*8];
#pragma unroll
            for (int g = 0; g < 4; ++g) {
                bfrag8 bh = *(const bfrag8*)&Bh[(g*16 + col)*56 + q*8];
                bfrag8 bl = *(const bfrag8*)&Bl[(g*16 + col)*56 + q*8];
                acc[g] = __builtin_amdgcn_mfma_f32_16x16x32_bf16(ah, bh, acc[g], 0,0,0);
                acc[g] = __builtin_amdgcn_mfma_f32_16x16x32_bf16(ah, bl, acc[g], 0,0,0);
                acc[g] = __builtin_amdgcn_mfma_f32_16x16x32_bf16(al, bh, acc[g], 0,0,0);
            }
            __syncthreads();
        }

        float hsum = 0.f;
#pragma unroll
        for (int r = 0; r < 4; ++r) {
            int b = b0 + w*16 + q*4 + r;
            float4 xv = *(const float4*)(price + (size_t)b*(Tn*4));
            float gates[4];
#pragma unroll
            for (int g = 0; g < 4; ++g) {
                int j = g*Hn + k0 + col;
                float4 wv = *(const float4*)(wih + (size_t)j*4);
                gates[g] = acc[g][r] + xv.x*wv.x + xv.y*wv.y + xv.z*wv.z + xv.w*wv.w
                         + bih[j] + bhh[j];
            }
            float c0 = sigf(gates[0]) * tanhfast(gates[2]);
            float h0 = sigf(gates[3]) * tanhfast(c0);
            cbuf[(size_t)b*Hn + k0 + col] = c0;
            hsum += h0;
        }
        hsum = wave_reduce(hsum);
        if (lane == 0) redk[w] = hsum;
        __syncthreads();
        if (tid == 0) atomicAdd(&Sh[0], redk[0]+redk[1]+redk[2]+redk[3]);
        return;
    }

    blk -= NB_GEMM;
    float* Sev     = ws + WS_SEV;
    float* rowsum  = ws + WS_RS;
    float* biassum = ws + WS_BS;

    if (blk < NB_ROWSUM) {                   // rowsum: rows for t=1..19
        int r    = blk*4 + (tid>>6);
        int lane = tid & 63;
        int t    = 1 + r/G4n;
        int j    = r - (t-1)*G4n;
        const float* base = whh + (size_t)t*G4n*Hn + (size_t)j*Hn;
        float s = 0.f;
#pragma unroll
        for (int i = 0; i < 3; ++i) {
            float4 v = *(const float4*)(base + (size_t)(lane + 64*i)*4);
            s += v.x + v.y + v.z + v.w;
        }
        s = wave_reduce(s);
        if (lane == 0) rowsum[t*G4n + j] = s;
    } else if (blk < NB_ROWSUM + NB_BIAS) {  // biassum
        int idx = (blk - NB_ROWSUM)*256 + tid;
        if (idx < Tn*G4n) biassum[idx] = bih[idx] + bhh[idx];
    } else {                                 // Sev[t], t=1..19, 64 blocks per t
        int sb = blk - NB_ROWSUM - NB_BIAS;
        int t  = 1 + (sb >> 6);
        int b0 = (sb & 63) * 16;
        float s = 0.f;
        for (int bb = 0; bb < 16; ++bb) {
            const float* base = ev + (size_t)(b0+bb)*(Tn*Hn) + (size_t)t*Hn;
            s += base[tid] + base[tid+256] + base[tid+512];
        }
        s = wave_reduce(s);
        if ((tid & 63) == 0) red[tid>>6] = s;
        __syncthreads();
        if (tid == 0) atomicAdd(&Sev[t], red[0]+red[1]+red[2]+red[3]);
    }
}

// ---------------- K2: persistent fused recurrence, t=1..19 ----------------
// 256 blocks x 768 threads; block owns b = blockIdx + 256e (e=0..3), k = tid.
// Barrier = token-packed relaxed 8B stores/loads. ZERO atomic RMWs in steady
// state (R3 lesson: 512 same-line far-atomic RMWs/step serialize at ~40ns
// each at the coherence point = the whole 20us/step cost).
__global__ __launch_bounds__(768) void k_steps(
    const float* __restrict__ price, const float* __restrict__ wih,
    const float* __restrict__ fcw,   const float* __restrict__ fcb,
    float* __restrict__ ws, float* __restrict__ out)
{
    __shared__ float pr[4][80];      // price rows for this block's 4 b's
    __shared__ float red[12];        // hsum block reduce
    __shared__ float redP[4];        // block 0: partial-poll reduce
    __shared__ float redF[4][12];
    __shared__ float shx;

    float* Sh  = ws + WS_SH;
    float* Sev = ws + WS_SEV;
    uint64_t* part  = (uint64_t*)(ws + WS_PART);
    uint64_t* bcast = (uint64_t*)(ws + WS_BCAST);
    const float* rowsum  = ws + WS_RS;
    const float* biassum = ws + WS_BS;
    float* cbuf = ws + WS_C;

    int blk = blockIdx.x, tid = threadIdx.x;
    int lane = tid & 63, wid = tid >> 6;
    int k = tid;

    if (tid < 320) {
        int e = tid / 80, r = tid - e*80;
        pr[e][r] = price[(size_t)(blk + 256*e)*(Tn*4) + r];
    }

    float c[4];
#pragma unroll
    for (int e = 0; e < 4; ++e)
        c[e] = cbuf[(size_t)(blk + 256*e)*Hn + k];

    float fcwk = fcw[k];
    float fcb0 = fcb[0];

    float hsum_prev = 0.f;
    float vout[4] = {0.f,0.f,0.f,0.f};

    for (int t = 1; t < Tn; ++t) {
        // ---- preload step-t coefficients + hx-independent gate bases ----
        const float* wih_t = wih + (size_t)t*G4n*4;
        float rsv[4], base[4][4];
#pragma unroll
        for (int g = 0; g < 4; ++g) {
            int j = g*Hn + k;
            float4 wv = *(const float4*)(wih_t + (size_t)j*4);
            rsv[g]   = rowsum[t*G4n + j];
            float bs = biassum[t*G4n + j];
#pragma unroll
            for (int e = 0; e < 4; ++e) {
                base[e][g] = pr[e][t*4+0]*wv.x + pr[e][t*4+1]*wv.y
                           + pr[e][t*4+2]*wv.z + pr[e][t*4+3]*wv.w + bs;
            }
        }

        // ---- publish previous step's block partial (token t-1) ----
        if (t >= 2) {
            float v = wave_reduce(hsum_prev);
            if (lane == 0) red[wid] = v;
            __syncthreads();
            if (tid == 0) {
                float tot = 0.f;
#pragma unroll
                for (int i = 0; i < 12; ++i) tot += red[i];
                __hip_atomic_store(&part[blk], pack_tv((unsigned)(t-1), tot),
                                   __ATOMIC_RELAXED, __HIP_MEMORY_SCOPE_AGENT);
            }
        }

        // ---- obtain hx_t ----
        if (blk == 0) {
            if (t >= 2) {
                if (tid < 256) {
                    uint64_t u;
                    do { u = __hip_atomic_load(&part[tid], __ATOMIC_RELAXED, __HIP_MEMORY_SCOPE_AGENT); }
                    while ((unsigned)(u >> 32) != (unsigned)(t-1));
                    float pv = wave_reduce(__uint_as_float((uint32_t)u));
                    if (lane == 0) redP[wid] = pv;
                }
                __syncthreads();
                if (tid == 0) {
                    float Shprev = redP[0]+redP[1]+redP[2]+redP[3];
                    float hx = Sev[t] + Shprev;
                    shx = hx;
                    __hip_atomic_store(bcast, pack_tv((unsigned)t, hx),
                                       __ATOMIC_RELAXED, __HIP_MEMORY_SCOPE_AGENT);
                }
            } else {
                if (tid == 0) {
                    float hx = Sev[1] + Sh[0];
                    shx = hx;
                    __hip_atomic_store(bcast, pack_tv(1u, hx),
                                       __ATOMIC_RELAXED, __HIP_MEMORY_SCOPE_AGENT);
                }
            }
            __syncthreads();
        } else {
            if (tid == 0) {
                uint64_t u;
                do { u = __hip_atomic_load(bcast, __ATOMIC_RELAXED, __HIP_MEMORY_SCOPE_AGENT); }
                while ((unsigned)(u >> 32) != (unsigned)t);
                shx = __uint_as_float((uint32_t)u);
            }
            __syncthreads();
        }
        float hx = shx;

        // ---- cell update ----
        float hsum = 0.f;
#pragma unroll
        for (int e = 0; e < 4; ++e) {
            float gi = base[e][0] + hx*rsv[0];
            float gf = base[e][1] + hx*rsv[1];
            float gg = base[e][2] + hx*rsv[2];
            float go = base[e][3] + hx*rsv[3];
            float cn = sigf(gf)*c[e] + sigf(gi)*tanhfast(gg);
            c[e] = cn;
            float h = sigf(go)*tanhfast(cn);
            hsum += h;
            if (t == Tn-1) vout[e] = wave_reduce(h * fcwk);
        }
        hsum_prev = hsum;
    }

    // epilogue: out[b] = h19[b,:].fc_w + fc_b
    if (lane == 0) {
#pragma unroll
        for (int e = 0; e < 4; ++e) redF[e][wid] = vout[e];
    }
    __syncthreads();
    if (tid < 4) {
        float tot = 0.f;
#pragma unroll
        for (int i = 0; i < 12; ++i) tot += redF[tid][i];
        out[blk + 256*tid] = tot + fcb0;
    }
}

extern "C" void kernel_launch(void* const* d_in, const int* in_sizes, int n_in,
                              void* d_out, int out_size, void* d_ws, size_t ws_size,
                              hipStream_t stream)
{
    const float* price = (const float*)d_in[0];
    const float* ev    = (const float*)d_in[1];
    const float* wih   = (const float*)d_in[2];
    const float* whh   = (const float*)d_in[3];
    const float* bih   = (const float*)d_in[4];
    const float* bhh   = (const float*)d_in[5];
    const float* fcw   = (const float*)d_in[6];
    const float* fcb   = (const float*)d_in[7];
    float* out = (float*)d_out;
    float* ws  = (float*)d_ws;

    k_init<<<1, 640, 0, stream>>>(ws);
    k_pre <<<NB_TOTAL, 256, 0, stream>>>(price, ev, wih, whh, bih, bhh, ws);
    k_steps<<<256, 768, 0, stream>>>(price, wih, fcw, fcb, ws, out);
}